// Round 3
// baseline (155.782 us; speedup 1.0000x reference)
//
#include <hip/hip_runtime.h>

// Problem constants (reference: B=4, C=64, H=512, W=512)
#define B_   4
#define C_   64
#define H_   512
#define W_   512
#define HW_  (H_ * W_)
#define KC   16           // input channels per K-chunk
#define NKC  (C_ / KC)    // 4 chunks

__device__ __forceinline__ void load_lds16(const float* g, float* l) {
    __builtin_amdgcn_global_load_lds(
        (const __attribute__((address_space(1))) void*)g,
        (__attribute__((address_space(3))) void*)l, 16, 0, 0);
}

// Pack weights for wave-uniform access: wp[g][c][j] = w[(g*8+j)*64 + c]
__global__ __launch_bounds__(256) void pack_w_kernel(
    const float* __restrict__ w, float* __restrict__ wp) {
    int i = blockIdx.x * 256 + threadIdx.x;   // 0..4095
    int o = i >> 6, c = i & 63;
    wp[(o >> 3) * 512 + c * 8 + (o & 7)] = w[i];
}

// out[b,o,h,w] = sum_c W[o][c] * x[b,c,h-1,w] + bias[o]   (h==0 -> bias only)
// Block = one (b,h): full 512-px row, all 64 out-ch. 512 threads = 8 waves.
// Wave wv owns out-channels wv*8..wv*8+7 (weights via uniform scalar loads).
// K-loop: 4 chunks x 16 ch, double-buffered LDS, counted vmcnt (never 0
// mid-loop) so stage(k+1) stays in flight across the barrier.
template <bool PACKED>
__global__ __launch_bounds__(512, 4) void shift_pw_kernel(
    const float* __restrict__ x,
    const float* __restrict__ wsrc,   // PACKED ? wp[g][c][8] : W[o][c]
    const float* __restrict__ bias,
    float* __restrict__ out) {

    __shared__ float xs[2][KC][W_];   // 2 x 32 KiB double buffer

    const int tid  = threadIdx.x;
    const int lane = tid & 63;
    const int wv   = tid >> 6;                     // 0..7
    const int wvu  = __builtin_amdgcn_readfirstlane(wv);
    const int ob   = wvu * 8;                      // this wave's out-ch base

    const int blk = blockIdx.x;
    const int h = blk & (H_ - 1);
    const int b = blk >> 9;

    // ---- bias preload (uniform scalar loads) ----
    float bv[8];
    #pragma unroll
    for (int oo = 0; oo < 8; ++oo) bv[oo] = bias[ob + oo];

    float* dst0 = out + ((size_t)b * C_ + ob) * HW_ + (size_t)h * W_;

    if (h == 0) {                                  // shifted-in zero row: bias only
        #pragma unroll
        for (int oo = 0; oo < 8; ++oo) {
            float4 v = make_float4(bv[oo], bv[oo], bv[oo], bv[oo]);
            *(float4*)(dst0 + (size_t)oo * HW_ + lane * 4)       = v;
            *(float4*)(dst0 + (size_t)oo * HW_ + 256 + lane * 4) = v;
        }
        return;
    }

    const float* xrow = x + ((size_t)b * C_) * HW_ + (size_t)(h - 1) * W_;

    // Stage chunk kc (16 ch x 512 px = 32 KiB) into xs[buf].
    // Wave wv loads channels {wv, wv+8}, each as 2 back-to-back 1KB instrs.
    auto STAGE = [&](int kc, int buf) {
        #pragma unroll
        for (int r = 0; r < 4; ++r) {
            const int c   = (r >> 1) * 8 + wv;     // wave-uniform
            const int px0 = (r & 1) * 256;
            load_lds16(xrow + (size_t)(kc * KC + c) * HW_ + px0 + lane * 4,
                       &xs[buf][c][px0]);
        }
    };

    float acc[8][8];                               // [out-ch][px: 0..3 lo, 4..7 hi]
    #pragma unroll
    for (int oo = 0; oo < 8; ++oo)
        #pragma unroll
        for (int j = 0; j < 8; ++j) acc[oo][j] = bv[oo];

    STAGE(0, 0);

    #pragma unroll
    for (int kc = 0; kc < NKC; ++kc) {
        const int cur = kc & 1;
        if (kc < NKC - 1) {
            STAGE(kc + 1, cur ^ 1);                // prefetch stays in flight
            asm volatile("s_waitcnt vmcnt(4)" ::: "memory");   // stage kc landed
        } else {
            asm volatile("s_waitcnt vmcnt(0)" ::: "memory");
        }
        __builtin_amdgcn_s_barrier();              // all waves' stage kc visible

        #pragma unroll
        for (int c = 0; c < KC; ++c) {
            const float4 xa = *(const float4*)&xs[cur][c][lane * 4];
            const float4 xb = *(const float4*)&xs[cur][c][256 + lane * 4];
            float wr[8];
            if constexpr (PACKED) {
                const float* wc_ = wsrc + wvu * 512 + (kc * KC + c) * 8;
                #pragma unroll
                for (int oo = 0; oo < 8; ++oo) wr[oo] = wc_[oo];   // uniform
            } else {
                #pragma unroll
                for (int oo = 0; oo < 8; ++oo)
                    wr[oo] = wsrc[(ob + oo) * C_ + kc * KC + c];   // uniform
            }
            const float xra[4] = {xa.x, xa.y, xa.z, xa.w};
            const float xrb[4] = {xb.x, xb.y, xb.z, xb.w};
            #pragma unroll
            for (int oo = 0; oo < 8; ++oo) {
                #pragma unroll
                for (int j = 0; j < 4; ++j) {
                    acc[oo][j]     = fmaf(wr[oo], xra[j], acc[oo][j]);
                    acc[oo][j + 4] = fmaf(wr[oo], xrb[j], acc[oo][j + 4]);
                }
            }
        }
        __builtin_amdgcn_s_barrier();              // buf free before overwrite
    }

    // ---- stores: per out-ch, two contiguous 1KB float4 instrs ----
    #pragma unroll
    for (int oo = 0; oo < 8; ++oo) {
        *(float4*)(dst0 + (size_t)oo * HW_ + lane * 4) =
            make_float4(acc[oo][0], acc[oo][1], acc[oo][2], acc[oo][3]);
        *(float4*)(dst0 + (size_t)oo * HW_ + 256 + lane * 4) =
            make_float4(acc[oo][4], acc[oo][5], acc[oo][6], acc[oo][7]);
    }
}

extern "C" void kernel_launch(void* const* d_in, const int* in_sizes, int n_in,
                              void* d_out, int out_size, void* d_ws, size_t ws_size,
                              hipStream_t stream) {
    const float* x    = (const float*)d_in[0];   // [4,64,512,512]
    const float* w    = (const float*)d_in[1];   // [64,64]
    const float* bias = (const float*)d_in[2];   // [64]
    float* out = (float*)d_out;

    const int grid = B_ * H_;                    // 2048 blocks

    if (ws_size >= C_ * C_ * sizeof(float)) {
        float* wp = (float*)d_ws;
        pack_w_kernel<<<16, 256, 0, stream>>>(w, wp);
        shift_pw_kernel<true><<<grid, 512, 0, stream>>>(x, wp, bias, out);
    } else {
        shift_pw_kernel<false><<<grid, 512, 0, stream>>>(x, w, bias, out);
    }
}

// Round 5
// 119.588 us; speedup vs baseline: 1.3027x; 1.3027x over previous
//
#include <hip/hip_runtime.h>

// Problem constants (reference: B=4, C=64, H=512, W=512)
#define B_   4
#define C_   64
#define H_   512
#define W_   512
#define HW_  (H_ * W_)
#define TP   256          // pixels per block (row segment)
#define NBW  (W_ / TP)    // 2 segments per row
#define OO   16           // out-channels per wave
#define NG   (C_ / OO)    // 4 wave-groups = waves per block

typedef float floatx4 __attribute__((ext_vector_type(4)));   // native vec for NT builtins

// Pack weights so each wave reads one 64B row per channel:
// wp[g][c][j] = w[(g*16+j)*64 + c]  -> s_load_dwordx16-able (uniform, contiguous)
__global__ __launch_bounds__(256) void pack_w_kernel(
    const float* __restrict__ w, float* __restrict__ wp) {
    int i = blockIdx.x * 256 + threadIdx.x;   // 0..4095
    int o = i >> 6, c = i & 63;
    wp[(o >> 4) * (C_ * OO) + c * OO + (o & 15)] = w[i];
}

// out[b,o,h,w] = sum_c W[o][c] * x[b,c,h-1,w] + bias[o]   (h==0 -> bias only)
// No LDS, no barriers. Block = 256 threads = 4 waves; wave wv owns out-channels
// wv*16..wv*16+15 (wave-uniform -> weights are SGPR broadcasts); lane owns 4 px.
// Per channel: 1 global_load_dwordx4 (x, shared by all 4 waves via L1/L2) +
// 1 s_load_dwordx16 (weights) + 64 FMA.
template <bool PACKED>
__global__ __launch_bounds__(256, 4) void shift_pw_kernel(
    const float* __restrict__ x,
    const float* __restrict__ wsrc,   // PACKED ? wp[g][c][16] : W[o][c]
    const float* __restrict__ bias,
    float* __restrict__ out) {

    const int tid  = threadIdx.x;
    const int lane = tid & 63;
    const int wv   = tid >> 6;                       // 0..3
    const int wvu  = __builtin_amdgcn_readfirstlane(wv);
    const int ob   = wvu * OO;                       // wave's out-ch base

    int blk = blockIdx.x;
    const int wseg = blk & (NBW - 1);
    blk >>= 1;                                       // / NBW
    const int h = blk & (H_ - 1);
    const int b = blk >> 9;                          // / H_
    const int w0 = wseg * TP + lane * 4;             // this lane's pixel base

    // ---- bias preload (uniform scalar loads) ----
    float bv[OO];
    #pragma unroll
    for (int oo = 0; oo < OO; ++oo) bv[oo] = bias[ob + oo];

    float* dst0 = out + ((size_t)b * C_ + ob) * HW_ + (size_t)h * W_ + w0;

    if (h == 0) {                                    // shifted-in zero row
        #pragma unroll
        for (int oo = 0; oo < OO; ++oo) {
            floatx4 v = {bv[oo], bv[oo], bv[oo], bv[oo]};
            __builtin_nontemporal_store(v, (floatx4*)(dst0 + (size_t)oo * HW_));
        }
        return;
    }

    const float* xp = x + ((size_t)b * C_) * HW_ + (size_t)(h - 1) * W_ + w0;

    float acc[OO][4];
    #pragma unroll
    for (int oo = 0; oo < OO; ++oo) {
        acc[oo][0] = bv[oo]; acc[oo][1] = bv[oo];
        acc[oo][2] = bv[oo]; acc[oo][3] = bv[oo];
    }

    const float* wg = PACKED ? (wsrc + wvu * (C_ * OO)) : wsrc;

    #pragma unroll 4
    for (int c = 0; c < C_; ++c) {
        const floatx4 xv = *(const floatx4*)(xp + (size_t)c * HW_);  // 4-way L1/L2 reuse
        float wr[OO];
        if constexpr (PACKED) {
            #pragma unroll
            for (int j = 0; j < OO; ++j) wr[j] = wg[c * OO + j];   // s_load_dwordx16
        } else {
            #pragma unroll
            for (int j = 0; j < OO; ++j) wr[j] = wg[(ob + j) * C_ + c];  // uniform
        }
        const float xr[4] = {xv.x, xv.y, xv.z, xv.w};
        #pragma unroll
        for (int oo = 0; oo < OO; ++oo)
            #pragma unroll
            for (int j = 0; j < 4; ++j)
                acc[oo][j] = fmaf(wr[oo], xr[j], acc[oo][j]);
    }

    // ---- stores: per oo, wave writes 1KB contiguous; NT (never re-read) ----
    #pragma unroll
    for (int oo = 0; oo < OO; ++oo) {
        floatx4 v = {acc[oo][0], acc[oo][1], acc[oo][2], acc[oo][3]};
        __builtin_nontemporal_store(v, (floatx4*)(dst0 + (size_t)oo * HW_));
    }
}

extern "C" void kernel_launch(void* const* d_in, const int* in_sizes, int n_in,
                              void* d_out, int out_size, void* d_ws, size_t ws_size,
                              hipStream_t stream) {
    const float* x    = (const float*)d_in[0];   // [4,64,512,512]
    const float* w    = (const float*)d_in[1];   // [64,64]
    const float* bias = (const float*)d_in[2];   // [64]
    float* out = (float*)d_out;

    const int grid = B_ * H_ * NBW;              // 4096 blocks

    if (ws_size >= C_ * C_ * sizeof(float)) {
        float* wp = (float*)d_ws;
        pack_w_kernel<<<16, 256, 0, stream>>>(w, wp);
        shift_pw_kernel<true><<<grid, 256, 0, stream>>>(x, wp, bias, out);
    } else {
        shift_pw_kernel<false><<<grid, 256, 0, stream>>>(x, w, bias, out);
    }
}

// Round 6
// 92.004 us; speedup vs baseline: 1.6932x; 1.2998x over previous
//
#include <hip/hip_runtime.h>

// Problem constants (reference: B=4, C=64, H=512, W=512)
#define B_   4
#define C_   64
#define H_   512
#define W_   512
#define HW_  (H_ * W_)

typedef float f32x16 __attribute__((ext_vector_type(16)));
typedef short bf16x8 __attribute__((ext_vector_type(8)));

__device__ __forceinline__ unsigned short f32_to_bf16_rne(float f) {
    union { float f; unsigned u; } v; v.f = f;
    unsigned u = v.u;
    u += 0x7fffu + ((u >> 16) & 1u);
    return (unsigned short)(u >> 16);
}

// Pack W into v_mfma_f32_32x32x16_bf16 A-fragment layout (bf16):
// frag f = m*4+kt; lane, j:  A[m*32 + (lane&31)][kt*16 + (lane>>5)*8 + j]
// flat: wpack[f*512 + lane*8 + j]   (8 KB total)
__global__ __launch_bounds__(512) void pack_w_kernel(
    const float* __restrict__ w, unsigned short* __restrict__ wpack) {
    const int t = threadIdx.x;          // 0..511
    const int f = t >> 6, lane = t & 63;
    const int m = f >> 2, kt = f & 3;
    const int o = m * 32 + (lane & 31);
    const int cb = kt * 16 + ((lane >> 5) << 3);
    #pragma unroll
    for (int j = 0; j < 8; ++j)
        wpack[f * 512 + lane * 8 + j] = f32_to_bf16_rne(w[o * C_ + cb + j]);
}

// out[b,o,h,w] = sum_c W[o][c] * x[b,c,h-1,w] + bias[o]   (h==0 -> bias only)
// MFMA version: no LDS, no barriers. Block = 256 thd = 4 waves; each wave owns
// 64 px x all 64 out-ch of one (b,h) row. Per wave: 8 W-frag loads (cached),
// 32 x dword-loads (gather into B-frag layout), 16 cvt_pk, 16 MFMA, 64 NT stores.
__global__ __launch_bounds__(256, 2) void shift_pw_mfma(
    const float* __restrict__ x,
    const unsigned short* __restrict__ wpack,
    const float* __restrict__ bias,
    float* __restrict__ out) {

    const int tid  = threadIdx.x;
    const int lane = tid & 63;
    const int wv   = __builtin_amdgcn_readfirstlane(tid >> 6);  // 0..3
    const int l31  = lane & 31;
    const int lh   = lane >> 5;                                 // 0/1

    const int seg = blockIdx.x & 1;          // px half of the row
    const int r   = blockIdx.x >> 1;
    const int h   = r & (H_ - 1);
    const int b   = r >> 9;
    const int px0 = seg * 256 + wv * 64;     // this wave's 64-px window

    // bias per C/D row: row = m*32 + (e&3) + 8*(e>>2) + 4*lh
    float bv[2][16];
    #pragma unroll
    for (int m = 0; m < 2; ++m)
        #pragma unroll
        for (int e = 0; e < 16; ++e)
            bv[m][e] = bias[m * 32 + (e & 3) + 8 * (e >> 2) + 4 * lh];

    float* obase = out + ((size_t)(b * C_ + 4 * lh) * HW_) + (size_t)h * W_ + px0 + l31;

    if (h == 0) {                            // shifted-in zero row: bias only
        #pragma unroll
        for (int m = 0; m < 2; ++m)
            #pragma unroll
            for (int e = 0; e < 16; ++e) {
                float* p = obase + (size_t)(m * 32 + (e & 3) + 8 * (e >> 2)) * HW_;
                __builtin_nontemporal_store(bv[m][e], p);
                __builtin_nontemporal_store(bv[m][e], p + 32);
            }
        return;
    }

    // W fragments (A-operand), 8 x dwordx4 from packed table (L2/L3-hot)
    bf16x8 wf[8];
    #pragma unroll
    for (int f = 0; f < 8; ++f)
        wf[f] = *(const bf16x8*)(wpack + f * 512 + lane * 8);

    f32x16 acc[2][2];                        // [m-tile][px-subtile]
    #pragma unroll
    for (int m = 0; m < 2; ++m)
        #pragma unroll
        for (int s = 0; s < 2; ++s)
            #pragma unroll
            for (int e = 0; e < 16; ++e)
                acc[m][s][e] = bv[m][e];

    // x base: B-frag element j of k-tile kt = x[c = kt*16 + lh*8 + j][px0 + s*32 + l31]
    const float* xb = x + ((size_t)(b * C_ + 8 * lh) * HW_) + (size_t)(h - 1) * W_ + px0 + l31;

    #pragma unroll
    for (int kt = 0; kt < 4; ++kt) {
        float xf[2][8];
        #pragma unroll
        for (int j = 0; j < 8; ++j) {
            const float* p = xb + (size_t)(kt * 16 + j) * HW_;
            xf[0][j] = p[0];                 // s=0 and s=1: 2x128B adjacent bursts
            xf[1][j] = p[32];
        }
        bf16x8 bf[2];
        #pragma unroll
        for (int s = 0; s < 2; ++s) {
            union { unsigned q[4]; bf16x8 v; } u;
            #pragma unroll
            for (int i = 0; i < 4; ++i) {
                unsigned d;
                asm("v_cvt_pk_bf16_f32 %0, %1, %2"
                    : "=v"(d) : "v"(xf[s][2 * i]), "v"(xf[s][2 * i + 1]));
                u.q[i] = d;
            }
            bf[s] = u.v;
        }
        #pragma unroll
        for (int m = 0; m < 2; ++m)
            #pragma unroll
            for (int s = 0; s < 2; ++s)
                acc[m][s] = __builtin_amdgcn_mfma_f32_32x32x16_bf16(
                    wf[m * 4 + kt], bf[s], acc[m][s], 0, 0, 0);
    }

    // stores: per (m,e): rows (e&3)+8*(e>>2)+4*lh+32*m; 2x128B NT segments
    #pragma unroll
    for (int m = 0; m < 2; ++m)
        #pragma unroll
        for (int e = 0; e < 16; ++e) {
            float* p = obase + (size_t)(m * 32 + (e & 3) + 8 * (e >> 2)) * HW_;
            __builtin_nontemporal_store(acc[m][0][e], p);
            __builtin_nontemporal_store(acc[m][1][e], p + 32);
        }
}

// ---- fp32 fallback (R5 kernel, proven) for tiny ws ----
__global__ __launch_bounds__(256, 4) void shift_pw_f32(
    const float* __restrict__ x, const float* __restrict__ wsrc,
    const float* __restrict__ bias, float* __restrict__ out) {
    const int tid = threadIdx.x, lane = tid & 63;
    const int wvu = __builtin_amdgcn_readfirstlane(tid >> 6);
    const int ob = wvu * 16;
    int blk = blockIdx.x;
    const int wseg = blk & 1; blk >>= 1;
    const int h = blk & (H_ - 1), b = blk >> 9;
    const int w0 = wseg * 256 + lane * 4;
    float bvv[16];
    #pragma unroll
    for (int oo = 0; oo < 16; ++oo) bvv[oo] = bias[ob + oo];
    float* dst0 = out + ((size_t)b * C_ + ob) * HW_ + (size_t)h * W_ + w0;
    if (h == 0) {
        #pragma unroll
        for (int oo = 0; oo < 16; ++oo) {
            float* p = dst0 + (size_t)oo * HW_;
            #pragma unroll
            for (int j = 0; j < 4; ++j) __builtin_nontemporal_store(bvv[oo], p + j);
        }
        return;
    }
    const float* xp = x + ((size_t)b * C_) * HW_ + (size_t)(h - 1) * W_ + w0;
    float acc[16][4];
    #pragma unroll
    for (int oo = 0; oo < 16; ++oo)
        #pragma unroll
        for (int j = 0; j < 4; ++j) acc[oo][j] = bvv[oo];
    #pragma unroll 4
    for (int c = 0; c < C_; ++c) {
        const float4 xv = *(const float4*)(xp + (size_t)c * HW_);
        const float xr[4] = {xv.x, xv.y, xv.z, xv.w};
        #pragma unroll
        for (int oo = 0; oo < 16; ++oo) {
            float wv_ = wsrc[(ob + oo) * C_ + c];
            #pragma unroll
            for (int j = 0; j < 4; ++j) acc[oo][j] = fmaf(wv_, xr[j], acc[oo][j]);
        }
    }
    #pragma unroll
    for (int oo = 0; oo < 16; ++oo) {
        float* p = dst0 + (size_t)oo * HW_;
        #pragma unroll
        for (int j = 0; j < 4; ++j) __builtin_nontemporal_store(acc[oo][j], p + j);
    }
}

extern "C" void kernel_launch(void* const* d_in, const int* in_sizes, int n_in,
                              void* d_out, int out_size, void* d_ws, size_t ws_size,
                              hipStream_t stream) {
    const float* x    = (const float*)d_in[0];   // [4,64,512,512]
    const float* w    = (const float*)d_in[1];   // [64,64]
    const float* bias = (const float*)d_in[2];   // [64]
    float* out = (float*)d_out;

    const int grid = B_ * H_ * 2;                // 4096 blocks

    if (ws_size >= 8 * 512 * sizeof(unsigned short)) {
        unsigned short* wpack = (unsigned short*)d_ws;
        pack_w_kernel<<<1, 512, 0, stream>>>(w, wpack);
        shift_pw_mfma<<<grid, 256, 0, stream>>>(x, wpack, bias, out);
    } else {
        shift_pw_f32<<<grid, 256, 0, stream>>>(x, w, bias, out);
    }
}

// Round 7
// 89.462 us; speedup vs baseline: 1.7413x; 1.0284x over previous
//
#include <hip/hip_runtime.h>

// Problem constants (reference: B=4, C=64, H=512, W=512)
#define B_   4
#define C_   64
#define H_   512
#define W_   512
#define HW_  (H_ * W_)

typedef float  f32x16 __attribute__((ext_vector_type(16)));
typedef float  floatx4 __attribute__((ext_vector_type(4)));
typedef short  bf16x8 __attribute__((ext_vector_type(8)));

// out[b,o,h,w] = sum_c W[o][c] * x[b,c,h-1,w] + bias[o]   (h==0 -> bias only)
// Single kernel, no LDS, no barriers, no workspace. Block = 256 thd = 4 waves;
// each wave owns 64 px x all 64 out-ch of one (b,h) row via 32x32x16 bf16 MFMA.
// W A-fragments are built in-register from the f32 weights (16 dwordx4 from a
// 16KB L1-hot table + v_cvt_pk_bf16_f32) -- no pack kernel, no serialization.
__global__ __launch_bounds__(256, 2) void shift_pw_mfma(
    const float* __restrict__ x,
    const float* __restrict__ w,      // [64][64] f32
    const float* __restrict__ bias,
    float* __restrict__ out) {

    const int tid  = threadIdx.x;
    const int lane = tid & 63;
    const int l31  = lane & 31;
    const int lh   = lane >> 5;                                 // 0/1
    const int wv   = __builtin_amdgcn_readfirstlane(tid >> 6);  // 0..3

    const int seg = blockIdx.x & 1;          // px half of the row
    const int r   = blockIdx.x >> 1;
    const int h   = r & (H_ - 1);
    const int b   = r >> 9;
    const int px0 = seg * 256 + wv * 64;     // this wave's 64-px window

    // bias per C/D row: row = m*32 + (e&3) + 8*(e>>2) + 4*lh
    float bv[2][16];
    #pragma unroll
    for (int m = 0; m < 2; ++m)
        #pragma unroll
        for (int e = 0; e < 16; ++e)
            bv[m][e] = bias[m * 32 + (e & 3) + 8 * (e >> 2) + 4 * lh];

    float* obase = out + ((size_t)(b * C_ + 4 * lh) * HW_) + (size_t)h * W_ + px0 + l31;

    if (h == 0) {                            // shifted-in zero row: bias only
        #pragma unroll
        for (int m = 0; m < 2; ++m)
            #pragma unroll
            for (int e = 0; e < 16; ++e) {
                float* p = obase + (size_t)(m * 32 + (e & 3) + 8 * (e >> 2)) * HW_;
                __builtin_nontemporal_store(bv[m][e], p);
                __builtin_nontemporal_store(bv[m][e], p + 32);
            }
        return;
    }

    // ---- W A-fragments, built in-register from f32 weights ----
    // frag f = m*4+kt; elem j: A[o = m*32 + l31][c = kt*16 + lh*8 + j]
    bf16x8 wf[8];
    #pragma unroll
    for (int m = 0; m < 2; ++m)
        #pragma unroll
        for (int kt = 0; kt < 4; ++kt) {
            const float* wp = w + (m * 32 + l31) * C_ + kt * 16 + lh * 8;
            const floatx4 a = *(const floatx4*)wp;        // 32B-aligned
            const floatx4 c = *(const floatx4*)(wp + 4);
            union { unsigned q[4]; bf16x8 v; } u;
            asm("v_cvt_pk_bf16_f32 %0, %1, %2" : "=v"(u.q[0]) : "v"(a.x), "v"(a.y));
            asm("v_cvt_pk_bf16_f32 %0, %1, %2" : "=v"(u.q[1]) : "v"(a.z), "v"(a.w));
            asm("v_cvt_pk_bf16_f32 %0, %1, %2" : "=v"(u.q[2]) : "v"(c.x), "v"(c.y));
            asm("v_cvt_pk_bf16_f32 %0, %1, %2" : "=v"(u.q[3]) : "v"(c.z), "v"(c.w));
            wf[m * 4 + kt] = u.v;
        }

    f32x16 acc[2][2];                        // [m-tile][px-subtile]
    #pragma unroll
    for (int m = 0; m < 2; ++m)
        #pragma unroll
        for (int s = 0; s < 2; ++s)
            #pragma unroll
            for (int e = 0; e < 16; ++e)
                acc[m][s][e] = bv[m][e];

    // x B-frag element j of k-tile kt: x[c = kt*16 + lh*8 + j][px0 + s*32 + l31]
    const float* xb = x + ((size_t)(b * C_ + 8 * lh) * HW_) + (size_t)(h - 1) * W_ + px0 + l31;

    #pragma unroll
    for (int kt = 0; kt < 4; ++kt) {
        float xf[2][8];
        #pragma unroll
        for (int j = 0; j < 8; ++j) {
            const float* p = xb + (size_t)(kt * 16 + j) * HW_;
            xf[0][j] = p[0];                 // 2x128B adjacent bursts per instr pair
            xf[1][j] = p[32];
        }
        bf16x8 bf[2];
        #pragma unroll
        for (int s = 0; s < 2; ++s) {
            union { unsigned q[4]; bf16x8 v; } u;
            #pragma unroll
            for (int i = 0; i < 4; ++i) {
                unsigned d;
                asm("v_cvt_pk_bf16_f32 %0, %1, %2"
                    : "=v"(d) : "v"(xf[s][2 * i]), "v"(xf[s][2 * i + 1]));
                u.q[i] = d;
            }
            bf[s] = u.v;
        }
        #pragma unroll
        for (int m = 0; m < 2; ++m)
            #pragma unroll
            for (int s = 0; s < 2; ++s)
                acc[m][s] = __builtin_amdgcn_mfma_f32_32x32x16_bf16(
                    wf[m * 4 + kt], bf[s], acc[m][s], 0, 0, 0);
    }

    // stores: per (m,e): row m*32 + (e&3)+8*(e>>2)+4*lh; 2x128B NT segments
    #pragma unroll
    for (int m = 0; m < 2; ++m)
        #pragma unroll
        for (int e = 0; e < 16; ++e) {
            float* p = obase + (size_t)(m * 32 + (e & 3) + 8 * (e >> 2)) * HW_;
            __builtin_nontemporal_store(acc[m][0][e], p);
            __builtin_nontemporal_store(acc[m][1][e], p + 32);
        }
}

extern "C" void kernel_launch(void* const* d_in, const int* in_sizes, int n_in,
                              void* d_out, int out_size, void* d_ws, size_t ws_size,
                              hipStream_t stream) {
    const float* x    = (const float*)d_in[0];   // [4,64,512,512]
    const float* w    = (const float*)d_in[1];   // [64,64]
    const float* bias = (const float*)d_in[2];   // [64]
    float* out = (float*)d_out;

    const int grid = B_ * H_ * 2;                // 4096 blocks
    shift_pw_mfma<<<grid, 256, 0, stream>>>(x, w, bias, out);
}